// Round 2
// baseline (54570.123 us; speedup 1.0000x reference)
//
#include <hip/hip_runtime.h>
#include <hip/hip_bf16.h>
#include <math.h>

#define N_WORDS 8192
#define LMAX    16
#define WED     506
#define WHD     512
#define CED     6
#define CHD     6
#define CVOC    128
#define TAG     64
#define XDIM    512      // WED + CHD
#define G4      2048     // 4*WHD
#define NWG     64       // workgroups for the word LSTM

__device__ __forceinline__ float fast_sigmoid(float x) { return 1.0f / (1.0f + __expf(-x)); }
__device__ __forceinline__ float fast_tanh(float x)    { return 2.0f / (1.0f + __expf(-2.0f * x)) - 1.0f; }

// ---------------- Kernel A: char-level LSTM, one thread per word ----------------
__global__ void __launch_bounds__(256) char_lstm_kernel(
    const int*   __restrict__ chars,     // [N, LMAX]
    const int*   __restrict__ lens,      // [N]
    const float* __restrict__ char_emb,  // [CVOC, CED]
    const float* __restrict__ cWih,      // [24, 6]
    const float* __restrict__ cWhh,      // [24, 6]
    const float* __restrict__ cb,        // [24]
    float*       __restrict__ h_char)    // [N, CHD]
{
    __shared__ float sWih[24][6], sWhh[24][6], sb[24], semb[CVOC][CED];
    int t = threadIdx.x;
    if (t < 144) { sWih[t / 6][t % 6] = cWih[t]; sWhh[t / 6][t % 6] = cWhh[t]; }
    if (t < 24) sb[t] = cb[t];
    for (int i = t; i < CVOC * CED; i += 256) semb[i / CED][i % CED] = char_emb[i];
    __syncthreads();

    int n = blockIdx.x * 256 + t;
    if (n >= N_WORDS) return;
    int len = lens[n];
    float h[CHD] = {0, 0, 0, 0, 0, 0};
    float c[CHD] = {0, 0, 0, 0, 0, 0};
    for (int l = 0; l < LMAX; ++l) {
        if (l >= len) break;  // once l >= len no further state updates occur
        int ch = chars[n * LMAX + l];
        float e[CED];
        #pragma unroll
        for (int k = 0; k < CED; ++k) e[k] = semb[ch][k];
        float pre[24];
        #pragma unroll
        for (int g = 0; g < 24; ++g) {
            float a = sb[g];
            #pragma unroll
            for (int k = 0; k < CED; ++k) a += e[k] * sWih[g][k];
            #pragma unroll
            for (int k = 0; k < CHD; ++k) a += h[k] * sWhh[g][k];
            pre[g] = a;
        }
        #pragma unroll
        for (int u = 0; u < CHD; ++u) {
            float ig = fast_sigmoid(pre[u]);
            float fg = fast_sigmoid(pre[6 + u]);
            float gg = fast_tanh(pre[12 + u]);
            float og = fast_sigmoid(pre[18 + u]);
            float cn = fg * c[u] + ig * gg;
            c[u] = cn;
            h[u] = og * fast_tanh(cn);
        }
    }
    for (int u = 0; u < CHD; ++u) h_char[n * CHD + u] = h[u];
}

// ---------------- Kernel B0: X = [word_emb gather | h_char] ----------------
__global__ void __launch_bounds__(256) build_x_kernel(
    const int*   __restrict__ words,
    const float* __restrict__ word_emb,  // [WV, WED]
    const float* __restrict__ h_char,    // [N, CHD]
    float*       __restrict__ X)         // [N, XDIM]
{
    long idx = (long)blockIdx.x * 256 + threadIdx.x;
    if (idx >= (long)N_WORDS * XDIM) return;
    int n = (int)(idx >> 9), k = (int)(idx & 511);
    float v;
    if (k < WED) v = word_emb[(long)words[n] * WED + k];
    else         v = h_char[n * CHD + (k - WED)];
    X[idx] = v;
}

// ---------------- Kernel B1: XP = X @ Wih^T + b, fp32 tiled GEMM ----------------
#define BM 64
#define BN 64
#define BK 16
__global__ void __launch_bounds__(256) xp_gemm_kernel(
    const float* __restrict__ X,    // [N, 512]
    const float* __restrict__ Wih,  // [2048, 512]
    const float* __restrict__ wb,   // [2048]
    float*       __restrict__ XP)   // [N, 2048]
{
    __shared__ float As[BM][BK + 1];
    __shared__ float Bs[BN][BK + 1];
    int tid = threadIdx.x;
    int bm = (blockIdx.x % (N_WORDS / BM)) * BM;
    int bn = (blockIdx.x / (N_WORDS / BM)) * BN;
    int ty = tid / 16, tx = tid % 16;
    float acc[4][4] = {};
    for (int k0 = 0; k0 < XDIM; k0 += BK) {
        #pragma unroll
        for (int i = 0; i < 4; ++i) {
            int e = tid + i * 256;
            int r = e >> 4, cc = e & 15;
            As[r][cc] = X[(long)(bm + r) * XDIM + k0 + cc];
            Bs[r][cc] = Wih[(long)(bn + r) * XDIM + k0 + cc];
        }
        __syncthreads();
        #pragma unroll
        for (int kk = 0; kk < BK; ++kk) {
            float a[4], b[4];
            #pragma unroll
            for (int i = 0; i < 4; ++i) a[i] = As[ty * 4 + i][kk];
            #pragma unroll
            for (int j = 0; j < 4; ++j) b[j] = Bs[tx * 4 + j][kk];
            #pragma unroll
            for (int i = 0; i < 4; ++i)
                #pragma unroll
                for (int j = 0; j < 4; ++j) acc[i][j] += a[i] * b[j];
        }
        __syncthreads();
    }
    #pragma unroll
    for (int i = 0; i < 4; ++i) {
        int m = bm + ty * 4 + i;
        #pragma unroll
        for (int j = 0; j < 4; ++j) {
            int g = bn + tx * 4 + j;
            XP[(long)m * G4 + g] = acc[i][j] + wb[g];
        }
    }
}

// ---------------- Kernel C: sequential word LSTM across 64 co-resident WGs ----------------
// WG wg owns hidden units j in [wg*8, wg*8+8). 32 lanes per unit, each lane holds a
// 16-wide K-chunk of all 4 gate rows of Whh in VGPRs (64 floats/lane). Cross-WG h
// broadcast through HS with agent-scope atomics + per-step release/acquire counter.
__global__ void __launch_bounds__(256, 1) word_lstm_kernel(
    const float* __restrict__ Whh,  // [2048, 512]
    const float* __restrict__ XP,   // [N, 2048]
    float*       HS,                // [N, 512]  (comm buffer + output)
    int*         counter)           // [N], zero-initialized
{
    int tid = threadIdx.x;
    int wg  = blockIdx.x;          // 0..63
    int ug  = tid >> 5;            // 0..7 unit-in-block
    int p   = tid & 31;            // K-part
    int j   = wg * 8 + ug;         // hidden unit 0..511
    int kbase = p * 16;

    float w[4][16];
    const int rows[4] = { j, 512 + j, 1024 + j, 1536 + j };
    #pragma unroll
    for (int r = 0; r < 4; ++r)
        for (int kk = 0; kk < 16; ++kk)
            w[r][kk] = Whh[(long)rows[r] * WHD + kbase + kk];

    float c = 0.0f;
    float h16[16];
    #pragma unroll
    for (int kk = 0; kk < 16; ++kk) h16[kk] = 0.0f;

    for (int t = 0; t < N_WORDS; ++t) {
        // xp loads depend only on t -> issue before the spin to hide HBM latency
        float xpi = XP[(long)t * G4 + j];
        float xpf = XP[(long)t * G4 + 512 + j];
        float xpg = XP[(long)t * G4 + 1024 + j];
        float xpo = XP[(long)t * G4 + 1536 + j];

        if (t > 0) {
            if (tid == 0) {
                while (__hip_atomic_load(&counter[t - 1], __ATOMIC_ACQUIRE,
                                         __HIP_MEMORY_SCOPE_AGENT) < NWG) {
                    __builtin_amdgcn_s_sleep(1);
                }
            }
            __syncthreads();
            float* hsrc = HS + (long)(t - 1) * WHD + kbase;
            #pragma unroll
            for (int kk = 0; kk < 16; ++kk)
                h16[kk] = __hip_atomic_load(&hsrc[kk], __ATOMIC_RELAXED,
                                            __HIP_MEMORY_SCOPE_AGENT);
        }

        float di = 0, df = 0, dg = 0, dq = 0;
        #pragma unroll
        for (int kk = 0; kk < 16; ++kk) {
            di += w[0][kk] * h16[kk];
            df += w[1][kk] * h16[kk];
            dg += w[2][kk] * h16[kk];
            dq += w[3][kk] * h16[kk];
        }
        // reduce over the 32 lanes of this unit (xor masks <32 stay in each half-wave)
        #pragma unroll
        for (int m = 16; m >= 1; m >>= 1) {
            di += __shfl_xor(di, m);
            df += __shfl_xor(df, m);
            dg += __shfl_xor(dg, m);
            dq += __shfl_xor(dq, m);
        }
        float ig = fast_sigmoid(xpi + di);
        float fg = fast_sigmoid(xpf + df);
        float gg = fast_tanh(xpg + dg);
        float og = fast_sigmoid(xpo + dq);
        c = fg * c + ig * gg;
        float hn = og * fast_tanh(c);

        if (p == 0)
            __hip_atomic_store(&HS[(long)t * WHD + j], hn, __ATOMIC_RELEASE,
                               __HIP_MEMORY_SCOPE_AGENT);
        __syncthreads();  // barrier drains vmcnt before the release-increment
        if (tid == 0)
            __hip_atomic_fetch_add(&counter[t], 1, __ATOMIC_RELEASE,
                                   __HIP_MEMORY_SCOPE_AGENT);
    }
}

// ---------------- Kernel D0: transpose out_W to [512][64] for coalesced reads ----------------
__global__ void __launch_bounds__(256) transpose_outw_kernel(
    const float* __restrict__ outW, float* __restrict__ outWT)
{
    int e = blockIdx.x * 256 + threadIdx.x;  // TAG*WHD
    if (e >= TAG * WHD) return;
    int g = e >> 9, k = e & 511;
    outWT[k * TAG + g] = outW[e];
}

// ---------------- Kernel D: logits + log_softmax, one wave per word ----------------
__global__ void __launch_bounds__(64) logits_kernel(
    const float* __restrict__ HS,
    const float* __restrict__ outWT,   // [512][64]
    const float* __restrict__ outb,    // [64]
    float*       __restrict__ out)     // [N, 64]
{
    int n = blockIdx.x;
    int g = threadIdx.x;
    const float* hrow = HS + (long)n * WHD;
    float acc = outb[g];
    #pragma unroll 8
    for (int k = 0; k < WHD; ++k) acc += hrow[k] * outWT[k * TAG + g];
    float m = acc;
    #pragma unroll
    for (int s = 32; s >= 1; s >>= 1) m = fmaxf(m, __shfl_xor(m, s));
    float ex = __expf(acc - m);
    float ssum = ex;
    #pragma unroll
    for (int s = 32; s >= 1; s >>= 1) ssum += __shfl_xor(ssum, s);
    out[(long)n * TAG + g] = acc - m - logf(ssum);
}

extern "C" void kernel_launch(void* const* d_in, const int* in_sizes, int n_in,
                              void* d_out, int out_size, void* d_ws, size_t ws_size,
                              hipStream_t stream)
{
    const int*   words = (const int*)   d_in[0];
    const int*   chars = (const int*)   d_in[1];
    const int*   lens  = (const int*)   d_in[2];
    const float* wemb  = (const float*) d_in[3];
    const float* cemb  = (const float*) d_in[4];
    const float* cWih  = (const float*) d_in[5];
    const float* cWhh  = (const float*) d_in[6];
    const float* cb    = (const float*) d_in[7];
    const float* wWih  = (const float*) d_in[8];
    const float* wWhh  = (const float*) d_in[9];
    const float* wb    = (const float*) d_in[10];
    const float* outW  = (const float*) d_in[11];
    const float* outb  = (const float*) d_in[12];
    float* out = (float*)d_out;

    // workspace layout (bytes)
    char* ws = (char*)d_ws;
    size_t off = 0;
    float* h_char = (float*)(ws + off); off += (size_t)N_WORDS * CHD * 4;      // 196,608
    float* X      = (float*)(ws + off); off += (size_t)N_WORDS * XDIM * 4;     // 16.8 MB
    float* XP     = (float*)(ws + off); off += (size_t)N_WORDS * G4 * 4;       // 67.1 MB
    float* HS     = (float*)(ws + off); off += (size_t)N_WORDS * WHD * 4;      // 16.8 MB
    int* counter  = (int*)  (ws + off); off += (size_t)N_WORDS * 4;            // 32 KB
    float* outWT  = (float*)(ws + off); off += (size_t)WHD * TAG * 4;          // 128 KB

    hipMemsetAsync(counter, 0, (size_t)N_WORDS * sizeof(int), stream);

    char_lstm_kernel<<<N_WORDS / 256, 256, 0, stream>>>(chars, lens, cemb, cWih, cWhh, cb, h_char);
    build_x_kernel<<<(N_WORDS * XDIM) / 256, 256, 0, stream>>>(words, wemb, h_char, X);
    xp_gemm_kernel<<<(N_WORDS / BM) * (G4 / BN), 256, 0, stream>>>(X, wWih, wb, XP);
    transpose_outw_kernel<<<(TAG * WHD) / 256, 256, 0, stream>>>(outW, outWT);
    word_lstm_kernel<<<NWG, 256, 0, stream>>>(wWhh, XP, HS, counter);
    logits_kernel<<<N_WORDS, 64, 0, stream>>>(HS, outWT, outb, out);
}

// Round 3
// 47401.901 us; speedup vs baseline: 1.1512x; 1.1512x over previous
//
#include <hip/hip_runtime.h>
#include <hip/hip_bf16.h>
#include <math.h>

#define N_WORDS 8192
#define LMAX    16
#define WED     506
#define WHD     512
#define CED     6
#define CHD     6
#define CVOC    128
#define TAG     64
#define XDIM    512      // WED + CHD
#define G4      2048     // 4*WHD
#define NWG     64       // workgroups for the word LSTM

__device__ __forceinline__ float fast_sigmoid(float x) { return 1.0f / (1.0f + __expf(-x)); }
__device__ __forceinline__ float fast_tanh(float x)    { return 2.0f / (1.0f + __expf(-2.0f * x)) - 1.0f; }

// ---------------- Kernel A: char-level LSTM, one thread per word ----------------
__global__ void __launch_bounds__(256) char_lstm_kernel(
    const int*   __restrict__ chars,     // [N, LMAX]
    const int*   __restrict__ lens,      // [N]
    const float* __restrict__ char_emb,  // [CVOC, CED]
    const float* __restrict__ cWih,      // [24, 6]
    const float* __restrict__ cWhh,      // [24, 6]
    const float* __restrict__ cb,        // [24]
    float*       __restrict__ h_char)    // [N, CHD]
{
    __shared__ float sWih[24][6], sWhh[24][6], sb[24], semb[CVOC][CED];
    int t = threadIdx.x;
    if (t < 144) { sWih[t / 6][t % 6] = cWih[t]; sWhh[t / 6][t % 6] = cWhh[t]; }
    if (t < 24) sb[t] = cb[t];
    for (int i = t; i < CVOC * CED; i += 256) semb[i / CED][i % CED] = char_emb[i];
    __syncthreads();

    int n = blockIdx.x * 256 + t;
    if (n >= N_WORDS) return;
    int len = lens[n];
    float h[CHD] = {0, 0, 0, 0, 0, 0};
    float c[CHD] = {0, 0, 0, 0, 0, 0};
    for (int l = 0; l < LMAX; ++l) {
        if (l >= len) break;  // once l >= len no further state updates occur
        int ch = chars[n * LMAX + l];
        float e[CED];
        #pragma unroll
        for (int k = 0; k < CED; ++k) e[k] = semb[ch][k];
        float pre[24];
        #pragma unroll
        for (int g = 0; g < 24; ++g) {
            float a = sb[g];
            #pragma unroll
            for (int k = 0; k < CED; ++k) a += e[k] * sWih[g][k];
            #pragma unroll
            for (int k = 0; k < CHD; ++k) a += h[k] * sWhh[g][k];
            pre[g] = a;
        }
        #pragma unroll
        for (int u = 0; u < CHD; ++u) {
            float ig = fast_sigmoid(pre[u]);
            float fg = fast_sigmoid(pre[6 + u]);
            float gg = fast_tanh(pre[12 + u]);
            float og = fast_sigmoid(pre[18 + u]);
            float cn = fg * c[u] + ig * gg;
            c[u] = cn;
            h[u] = og * fast_tanh(cn);
        }
    }
    for (int u = 0; u < CHD; ++u) h_char[n * CHD + u] = h[u];
}

// ---------------- Kernel B0: X = [word_emb gather | h_char] ----------------
__global__ void __launch_bounds__(256) build_x_kernel(
    const int*   __restrict__ words,
    const float* __restrict__ word_emb,  // [WV, WED]
    const float* __restrict__ h_char,    // [N, CHD]
    float*       __restrict__ X)         // [N, XDIM]
{
    long idx = (long)blockIdx.x * 256 + threadIdx.x;
    if (idx >= (long)N_WORDS * XDIM) return;
    int n = (int)(idx >> 9), k = (int)(idx & 511);
    float v;
    if (k < WED) v = word_emb[(long)words[n] * WED + k];
    else         v = h_char[n * CHD + (k - WED)];
    X[idx] = v;
}

// ---------------- Kernel B1: XP4 = X @ Wih^T + b, fp32 tiled GEMM ----------------
// Epilogue writes gate-interleaved layout XP4[t][unit][gate] so the word LSTM
// reads one float4 per thread per step.
#define BM 64
#define BN 64
#define BK 16
__global__ void __launch_bounds__(256) xp_gemm_kernel(
    const float* __restrict__ X,    // [N, 512]
    const float* __restrict__ Wih,  // [2048, 512]
    const float* __restrict__ wb,   // [2048]
    float*       __restrict__ XP4)  // [N, 512, 4]
{
    __shared__ float As[BM][BK + 1];
    __shared__ float Bs[BN][BK + 1];
    int tid = threadIdx.x;
    int bm = (blockIdx.x % (N_WORDS / BM)) * BM;
    int bn = (blockIdx.x / (N_WORDS / BM)) * BN;
    int ty = tid / 16, tx = tid % 16;
    float acc[4][4] = {};
    for (int k0 = 0; k0 < XDIM; k0 += BK) {
        #pragma unroll
        for (int i = 0; i < 4; ++i) {
            int e = tid + i * 256;
            int r = e >> 4, cc = e & 15;
            As[r][cc] = X[(long)(bm + r) * XDIM + k0 + cc];
            Bs[r][cc] = Wih[(long)(bn + r) * XDIM + k0 + cc];
        }
        __syncthreads();
        #pragma unroll
        for (int kk = 0; kk < BK; ++kk) {
            float a[4], b[4];
            #pragma unroll
            for (int i = 0; i < 4; ++i) a[i] = As[ty * 4 + i][kk];
            #pragma unroll
            for (int j = 0; j < 4; ++j) b[j] = Bs[tx * 4 + j][kk];
            #pragma unroll
            for (int i = 0; i < 4; ++i)
                #pragma unroll
                for (int j = 0; j < 4; ++j) acc[i][j] += a[i] * b[j];
        }
        __syncthreads();
    }
    #pragma unroll
    for (int i = 0; i < 4; ++i) {
        int m = bm + ty * 4 + i;
        #pragma unroll
        for (int j = 0; j < 4; ++j) {
            int g = bn + tx * 4 + j;
            int unit = g & 511, gate = g >> 9;
            XP4[((long)m * WHD + unit) * 4 + gate] = acc[i][j] + wb[g];
        }
    }
}

// ---------------- Kernel C: sequential word LSTM, sentinel free-running dataflow ----------------
// WG wg owns hidden units j in [wg*8, wg*8+8). 32 lanes per unit, each lane holds a
// 16-wide K-chunk of all 4 gate rows of Whh in VGPRs. No barriers, no flags: every
// HS element is written exactly once as h+2.0 (in (1,3)); HS is pre-zeroed, so
// consumers spin directly on the data with relaxed agent-scope loads (v > 0.5 == ready).
// This fuses flag and data into ONE LLC round trip per step.
__global__ void __launch_bounds__(256, 1) word_lstm_kernel(
    const float* __restrict__ Whh,  // [2048, 512]
    const float* __restrict__ XP4,  // [N, 512, 4] gate-interleaved
    float*       HS)                // [N, 512]; stores h+2.0; pre-zeroed
{
    const int tid = threadIdx.x;
    const int wg  = blockIdx.x;      // 0..63
    const int ug  = tid >> 5;        // 0..7 unit-in-block
    const int p   = tid & 31;        // K-part
    const int j   = wg * 8 + ug;     // hidden unit 0..511
    const int kbase = p * 16;

    float w[4][16];
    #pragma unroll
    for (int r = 0; r < 4; ++r) {
        const float* src = Whh + (long)(r * 512 + j) * WHD + kbase;
        #pragma unroll
        for (int kk = 0; kk < 16; ++kk) w[r][kk] = src[kk];
    }

    float c = 0.0f;
    float h16[16];
    #pragma unroll
    for (int kk = 0; kk < 16; ++kk) h16[kk] = 0.0f;

    for (int t = 0; t < N_WORDS; ++t) {
        // xp load depends only on t -> issue before the poll so HBM latency hides
        const float4 xp = *(const float4*)(XP4 + ((long)t * WHD + j) * 4);

        if (t > 0) {
            const float* hsrc = HS + (long)(t - 1) * WHD + kbase;
            float v[16];
            bool ready = false;
            while (!ready) {
                ready = true;
                #pragma unroll
                for (int kk = 0; kk < 16; ++kk) {
                    v[kk] = __hip_atomic_load(&hsrc[kk], __ATOMIC_RELAXED,
                                              __HIP_MEMORY_SCOPE_AGENT);
                    ready = ready && (v[kk] > 0.5f);
                }
            }
            #pragma unroll
            for (int kk = 0; kk < 16; ++kk) h16[kk] = v[kk] - 2.0f;
        }

        float di = 0, df = 0, dg = 0, dq = 0;
        #pragma unroll
        for (int kk = 0; kk < 16; ++kk) {
            di = fmaf(w[0][kk], h16[kk], di);
            df = fmaf(w[1][kk], h16[kk], df);
            dg = fmaf(w[2][kk], h16[kk], dg);
            dq = fmaf(w[3][kk], h16[kk], dq);
        }
        // reduce over the 32 lanes of this unit (xor masks <32 stay in each half-wave)
        #pragma unroll
        for (int m = 16; m >= 1; m >>= 1) {
            di += __shfl_xor(di, m);
            df += __shfl_xor(df, m);
            dg += __shfl_xor(dg, m);
            dq += __shfl_xor(dq, m);
        }
        float ig = fast_sigmoid(xp.x + di);
        float fg = fast_sigmoid(xp.y + df);
        float gg = fast_tanh(xp.z + dg);
        float og = fast_sigmoid(xp.w + dq);
        c = fg * c + ig * gg;
        float hn = og * fast_tanh(c);

        if (p == 0)
            __hip_atomic_store(&HS[(long)t * WHD + j], hn + 2.0f, __ATOMIC_RELAXED,
                               __HIP_MEMORY_SCOPE_AGENT);
    }
}

// ---------------- Kernel D0: transpose out_W to [512][64] for coalesced reads ----------------
__global__ void __launch_bounds__(256) transpose_outw_kernel(
    const float* __restrict__ outW, float* __restrict__ outWT)
{
    int e = blockIdx.x * 256 + threadIdx.x;  // TAG*WHD
    if (e >= TAG * WHD) return;
    int g = e >> 9, k = e & 511;
    outWT[k * TAG + g] = outW[e];
}

// ---------------- Kernel D: logits + log_softmax, one wave per word ----------------
// HS holds h+2.0 -> subtract the offset inline.
__global__ void __launch_bounds__(64) logits_kernel(
    const float* __restrict__ HS,
    const float* __restrict__ outWT,   // [512][64]
    const float* __restrict__ outb,    // [64]
    float*       __restrict__ out)     // [N, 64]
{
    int n = blockIdx.x;
    int g = threadIdx.x;
    const float* hrow = HS + (long)n * WHD;
    float acc = outb[g];
    #pragma unroll 8
    for (int k = 0; k < WHD; ++k) acc += (hrow[k] - 2.0f) * outWT[k * TAG + g];
    float m = acc;
    #pragma unroll
    for (int s = 32; s >= 1; s >>= 1) m = fmaxf(m, __shfl_xor(m, s));
    float ex = __expf(acc - m);
    float ssum = ex;
    #pragma unroll
    for (int s = 32; s >= 1; s >>= 1) ssum += __shfl_xor(ssum, s);
    out[(long)n * TAG + g] = acc - m - logf(ssum);
}

extern "C" void kernel_launch(void* const* d_in, const int* in_sizes, int n_in,
                              void* d_out, int out_size, void* d_ws, size_t ws_size,
                              hipStream_t stream)
{
    const int*   words = (const int*)   d_in[0];
    const int*   chars = (const int*)   d_in[1];
    const int*   lens  = (const int*)   d_in[2];
    const float* wemb  = (const float*) d_in[3];
    const float* cemb  = (const float*) d_in[4];
    const float* cWih  = (const float*) d_in[5];
    const float* cWhh  = (const float*) d_in[6];
    const float* cb    = (const float*) d_in[7];
    const float* wWih  = (const float*) d_in[8];
    const float* wWhh  = (const float*) d_in[9];
    const float* wb    = (const float*) d_in[10];
    const float* outW  = (const float*) d_in[11];
    const float* outb  = (const float*) d_in[12];
    float* out = (float*)d_out;

    // workspace layout (bytes)
    char* ws = (char*)d_ws;
    size_t off = 0;
    float* h_char = (float*)(ws + off); off += (size_t)N_WORDS * CHD * 4;      // 196,608
    float* X      = (float*)(ws + off); off += (size_t)N_WORDS * XDIM * 4;     // 16.8 MB
    float* XP4    = (float*)(ws + off); off += (size_t)N_WORDS * G4 * 4;       // 67.1 MB
    float* HS     = (float*)(ws + off); off += (size_t)N_WORDS * WHD * 4;      // 16.8 MB
    float* outWT  = (float*)(ws + off); off += (size_t)WHD * TAG * 4;          // 128 KB

    // HS must be zero so the sentinel protocol (stored h+2 > 0.5) is well-defined.
    hipMemsetAsync(HS, 0, (size_t)N_WORDS * WHD * sizeof(float), stream);

    char_lstm_kernel<<<N_WORDS / 256, 256, 0, stream>>>(chars, lens, cemb, cWih, cWhh, cb, h_char);
    build_x_kernel<<<(N_WORDS * XDIM) / 256, 256, 0, stream>>>(words, wemb, h_char, X);
    xp_gemm_kernel<<<(N_WORDS / BM) * (G4 / BN), 256, 0, stream>>>(X, wWih, wb, XP4);
    transpose_outw_kernel<<<(TAG * WHD) / 256, 256, 0, stream>>>(outW, outWT);
    word_lstm_kernel<<<NWG, 256, 0, stream>>>(wWhh, XP4, HS);
    logits_kernel<<<N_WORDS, 64, 0, stream>>>(HS, outWT, outb, out);
}

// Round 4
// 18050.916 us; speedup vs baseline: 3.0231x; 2.6260x over previous
//
#include <hip/hip_runtime.h>
#include <hip/hip_bf16.h>
#include <math.h>

#define N_WORDS 8192
#define LMAX    16
#define WED     506
#define WHD     512
#define CED     6
#define CHD     6
#define CVOC    128
#define TAG     64
#define XDIM    512      // WED + CHD
#define G4      2048     // 4*WHD
#define NWG     64       // workgroups for the word LSTM

__device__ __forceinline__ float fast_sigmoid(float x) { return 1.0f / (1.0f + __expf(-x)); }
__device__ __forceinline__ float fast_tanh(float x)    { return 2.0f / (1.0f + __expf(-2.0f * x)) - 1.0f; }

// ---------------- Kernel A: char-level LSTM, one thread per word ----------------
__global__ void __launch_bounds__(256) char_lstm_kernel(
    const int*   __restrict__ chars,     // [N, LMAX]
    const int*   __restrict__ lens,      // [N]
    const float* __restrict__ char_emb,  // [CVOC, CED]
    const float* __restrict__ cWih,      // [24, 6]
    const float* __restrict__ cWhh,      // [24, 6]
    const float* __restrict__ cb,        // [24]
    float*       __restrict__ h_char)    // [N, CHD]
{
    __shared__ float sWih[24][6], sWhh[24][6], sb[24], semb[CVOC][CED];
    int t = threadIdx.x;
    if (t < 144) { sWih[t / 6][t % 6] = cWih[t]; sWhh[t / 6][t % 6] = cWhh[t]; }
    if (t < 24) sb[t] = cb[t];
    for (int i = t; i < CVOC * CED; i += 256) semb[i / CED][i % CED] = char_emb[i];
    __syncthreads();

    int n = blockIdx.x * 256 + t;
    if (n >= N_WORDS) return;
    int len = lens[n];
    float h[CHD] = {0, 0, 0, 0, 0, 0};
    float c[CHD] = {0, 0, 0, 0, 0, 0};
    for (int l = 0; l < LMAX; ++l) {
        if (l >= len) break;  // once l >= len no further state updates occur
        int ch = chars[n * LMAX + l];
        float e[CED];
        #pragma unroll
        for (int k = 0; k < CED; ++k) e[k] = semb[ch][k];
        float pre[24];
        #pragma unroll
        for (int g = 0; g < 24; ++g) {
            float a = sb[g];
            #pragma unroll
            for (int k = 0; k < CED; ++k) a += e[k] * sWih[g][k];
            #pragma unroll
            for (int k = 0; k < CHD; ++k) a += h[k] * sWhh[g][k];
            pre[g] = a;
        }
        #pragma unroll
        for (int u = 0; u < CHD; ++u) {
            float ig = fast_sigmoid(pre[u]);
            float fg = fast_sigmoid(pre[6 + u]);
            float gg = fast_tanh(pre[12 + u]);
            float og = fast_sigmoid(pre[18 + u]);
            float cn = fg * c[u] + ig * gg;
            c[u] = cn;
            h[u] = og * fast_tanh(cn);
        }
    }
    for (int u = 0; u < CHD; ++u) h_char[n * CHD + u] = h[u];
}

// ---------------- Kernel B0: X = [word_emb gather | h_char] ----------------
__global__ void __launch_bounds__(256) build_x_kernel(
    const int*   __restrict__ words,
    const float* __restrict__ word_emb,  // [WV, WED]
    const float* __restrict__ h_char,    // [N, CHD]
    float*       __restrict__ X)         // [N, XDIM]
{
    long idx = (long)blockIdx.x * 256 + threadIdx.x;
    if (idx >= (long)N_WORDS * XDIM) return;
    int n = (int)(idx >> 9), k = (int)(idx & 511);
    float v;
    if (k < WED) v = word_emb[(long)words[n] * WED + k];
    else         v = h_char[n * CHD + (k - WED)];
    X[idx] = v;
}

// ---------------- Kernel B1: XP4 = X @ Wih^T + b, fp32 tiled GEMM ----------------
// Epilogue writes gate-interleaved layout XP4[t][unit][gate] so the word LSTM
// reads one float4 per thread per step.
#define BM 64
#define BN 64
#define BK 16
__global__ void __launch_bounds__(256) xp_gemm_kernel(
    const float* __restrict__ X,    // [N, 512]
    const float* __restrict__ Wih,  // [2048, 512]
    const float* __restrict__ wb,   // [2048]
    float*       __restrict__ XP4)  // [N, 512, 4]
{
    __shared__ float As[BM][BK + 1];
    __shared__ float Bs[BN][BK + 1];
    int tid = threadIdx.x;
    int bm = (blockIdx.x % (N_WORDS / BM)) * BM;
    int bn = (blockIdx.x / (N_WORDS / BM)) * BN;
    int ty = tid / 16, tx = tid % 16;
    float acc[4][4] = {};
    for (int k0 = 0; k0 < XDIM; k0 += BK) {
        #pragma unroll
        for (int i = 0; i < 4; ++i) {
            int e = tid + i * 256;
            int r = e >> 4, cc = e & 15;
            As[r][cc] = X[(long)(bm + r) * XDIM + k0 + cc];
            Bs[r][cc] = Wih[(long)(bn + r) * XDIM + k0 + cc];
        }
        __syncthreads();
        #pragma unroll
        for (int kk = 0; kk < BK; ++kk) {
            float a[4], b[4];
            #pragma unroll
            for (int i = 0; i < 4; ++i) a[i] = As[ty * 4 + i][kk];
            #pragma unroll
            for (int j = 0; j < 4; ++j) b[j] = Bs[tx * 4 + j][kk];
            #pragma unroll
            for (int i = 0; i < 4; ++i)
                #pragma unroll
                for (int j = 0; j < 4; ++j) acc[i][j] += a[i] * b[j];
        }
        __syncthreads();
    }
    #pragma unroll
    for (int i = 0; i < 4; ++i) {
        int m = bm + ty * 4 + i;
        #pragma unroll
        for (int j = 0; j < 4; ++j) {
            int g = bn + tx * 4 + j;
            int unit = g & 511, gate = g >> 9;
            XP4[((long)m * WHD + unit) * 4 + gate] = acc[i][j] + wb[g];
        }
    }
}

// ---------------- Kernel C: sequential word LSTM, low-contention sentinel dataflow ----------------
// WG wg owns hidden units j in [wg*8, wg*8+8). Lane p of each unit owns the STRIDED
// K-set {p + 32*kk : kk in [0,16)} (bank-conflict-free LDS reads). Sentinel protocol:
// HS[t][u] is written exactly once as h+2.0 (in [1,3]); HS pre-zeroed; ready <=> v>0.5.
// Contention control: ONLY wave 0 of each WG polls HS, with 4 fully-coalesced u64
// agent-scope loads per lane (1 line-request per 128B line per WG per round), then
// broadcasts h-2.0 through LDS to the other waves.
__global__ void __launch_bounds__(256, 1) word_lstm_kernel(
    const float* __restrict__ Whh,  // [2048, 512]
    const float* __restrict__ XP4,  // [N, 512, 4] gate-interleaved
    float*       HS)                // [N, 512]; stores h+2.0; pre-zeroed
{
    __shared__ float hbuf[WHD];     // h[t-1] (offset removed)

    const int tid = threadIdx.x;
    const int wg  = blockIdx.x;      // 0..63
    const int ug  = tid >> 5;        // 0..7 unit-in-block
    const int p   = tid & 31;        // K-part within unit
    const int j   = wg * 8 + ug;     // hidden unit 0..511

    // weights for the strided K-set
    float w[4][16];
    #pragma unroll
    for (int r = 0; r < 4; ++r) {
        const float* src = Whh + (long)(r * 512 + j) * WHD + p;
        #pragma unroll
        for (int kk = 0; kk < 16; ++kk) w[r][kk] = src[kk * 32];
    }

    float c = 0.0f;
    float h16[16];
    #pragma unroll
    for (int kk = 0; kk < 16; ++kk) h16[kk] = 0.0f;

    for (int t = 0; t < N_WORDS; ++t) {
        // xp load depends only on t -> issue before the poll so HBM latency hides
        const float4 xp = *(const float4*)(XP4 + ((long)t * WHD + j) * 4);

        if (t > 0) {
            if (tid < 64) {
                // lane l: u64 #i at float offset i*128 + 2*l  (contiguous per inst)
                const unsigned long long* hrow =
                    (const unsigned long long*)(HS + (long)(t - 1) * WHD);
                float lo[4], hi[4];
                bool ready = false;
                while (!ready) {
                    unsigned long long q[4];
                    #pragma unroll
                    for (int i = 0; i < 4; ++i)
                        q[i] = __hip_atomic_load(&hrow[i * 64 + tid], __ATOMIC_RELAXED,
                                                 __HIP_MEMORY_SCOPE_AGENT);
                    ready = true;
                    #pragma unroll
                    for (int i = 0; i < 4; ++i) {
                        lo[i] = __uint_as_float((unsigned)(q[i] & 0xffffffffu));
                        hi[i] = __uint_as_float((unsigned)(q[i] >> 32));
                        ready = ready && (lo[i] > 0.5f) && (hi[i] > 0.5f);
                    }
                }
                #pragma unroll
                for (int i = 0; i < 4; ++i) {
                    hbuf[i * 128 + 2 * tid]     = lo[i] - 2.0f;
                    hbuf[i * 128 + 2 * tid + 1] = hi[i] - 2.0f;
                }
            }
            __syncthreads();
            #pragma unroll
            for (int kk = 0; kk < 16; ++kk) h16[kk] = hbuf[p + 32 * kk];
        }

        float di = 0, df = 0, dg = 0, dq = 0;
        #pragma unroll
        for (int kk = 0; kk < 16; ++kk) {
            di = fmaf(w[0][kk], h16[kk], di);
            df = fmaf(w[1][kk], h16[kk], df);
            dg = fmaf(w[2][kk], h16[kk], dg);
            dq = fmaf(w[3][kk], h16[kk], dq);
        }
        // reduce over the 32 lanes of this unit (xor masks <32 stay in each half-wave)
        #pragma unroll
        for (int m = 16; m >= 1; m >>= 1) {
            di += __shfl_xor(di, m);
            df += __shfl_xor(df, m);
            dg += __shfl_xor(dg, m);
            dq += __shfl_xor(dq, m);
        }
        float ig = fast_sigmoid(xp.x + di);
        float fg = fast_sigmoid(xp.y + df);
        float gg = fast_tanh(xp.z + dg);
        float og = fast_sigmoid(xp.w + dq);
        c = fg * c + ig * gg;
        float hn = og * fast_tanh(c);

        if (p == 0)
            __hip_atomic_store(&HS[(long)t * WHD + j], hn + 2.0f, __ATOMIC_RELAXED,
                               __HIP_MEMORY_SCOPE_AGENT);
        // NOTE: no trailing barrier needed. Wave 0 only overwrites hbuf for step t+1
        // after ALL 512 h[t] values are globally visible, which implies every wave
        // (including ours) has already consumed its step-t LDS reads.
    }
}

// ---------------- Kernel D0: transpose out_W to [512][64] for coalesced reads ----------------
__global__ void __launch_bounds__(256) transpose_outw_kernel(
    const float* __restrict__ outW, float* __restrict__ outWT)
{
    int e = blockIdx.x * 256 + threadIdx.x;  // TAG*WHD
    if (e >= TAG * WHD) return;
    int g = e >> 9, k = e & 511;
    outWT[k * TAG + g] = outW[e];
}

// ---------------- Kernel D: logits + log_softmax, one wave per word ----------------
// HS holds h+2.0 -> subtract the offset inline.
__global__ void __launch_bounds__(64) logits_kernel(
    const float* __restrict__ HS,
    const float* __restrict__ outWT,   // [512][64]
    const float* __restrict__ outb,    // [64]
    float*       __restrict__ out)     // [N, 64]
{
    int n = blockIdx.x;
    int g = threadIdx.x;
    const float* hrow = HS + (long)n * WHD;
    float acc = outb[g];
    #pragma unroll 8
    for (int k = 0; k < WHD; ++k) acc += (hrow[k] - 2.0f) * outWT[k * TAG + g];
    float m = acc;
    #pragma unroll
    for (int s = 32; s >= 1; s >>= 1) m = fmaxf(m, __shfl_xor(m, s));
    float ex = __expf(acc - m);
    float ssum = ex;
    #pragma unroll
    for (int s = 32; s >= 1; s >>= 1) ssum += __shfl_xor(ssum, s);
    out[(long)n * TAG + g] = acc - m - logf(ssum);
}

extern "C" void kernel_launch(void* const* d_in, const int* in_sizes, int n_in,
                              void* d_out, int out_size, void* d_ws, size_t ws_size,
                              hipStream_t stream)
{
    const int*   words = (const int*)   d_in[0];
    const int*   chars = (const int*)   d_in[1];
    const int*   lens  = (const int*)   d_in[2];
    const float* wemb  = (const float*) d_in[3];
    const float* cemb  = (const float*) d_in[4];
    const float* cWih  = (const float*) d_in[5];
    const float* cWhh  = (const float*) d_in[6];
    const float* cb    = (const float*) d_in[7];
    const float* wWih  = (const float*) d_in[8];
    const float* wWhh  = (const float*) d_in[9];
    const float* wb    = (const float*) d_in[10];
    const float* outW  = (const float*) d_in[11];
    const float* outb  = (const float*) d_in[12];
    float* out = (float*)d_out;

    // workspace layout (bytes)
    char* ws = (char*)d_ws;
    size_t off = 0;
    float* h_char = (float*)(ws + off); off += (size_t)N_WORDS * CHD * 4;      // 196,608
    float* X      = (float*)(ws + off); off += (size_t)N_WORDS * XDIM * 4;     // 16.8 MB
    float* XP4    = (float*)(ws + off); off += (size_t)N_WORDS * G4 * 4;       // 67.1 MB
    float* HS     = (float*)(ws + off); off += (size_t)N_WORDS * WHD * 4;      // 16.8 MB
    float* outWT  = (float*)(ws + off); off += (size_t)WHD * TAG * 4;          // 128 KB

    // HS must be zero so the sentinel protocol (stored h+2 > 0.5) is well-defined.
    hipMemsetAsync(HS, 0, (size_t)N_WORDS * WHD * sizeof(float), stream);

    char_lstm_kernel<<<N_WORDS / 256, 256, 0, stream>>>(chars, lens, cemb, cWih, cWhh, cb, h_char);
    build_x_kernel<<<(N_WORDS * XDIM) / 256, 256, 0, stream>>>(words, wemb, h_char, X);
    xp_gemm_kernel<<<(N_WORDS / BM) * (G4 / BN), 256, 0, stream>>>(X, wWih, wb, XP4);
    transpose_outw_kernel<<<(TAG * WHD) / 256, 256, 0, stream>>>(outW, outWT);
    word_lstm_kernel<<<NWG, 256, 0, stream>>>(wWhh, XP4, HS);
    logits_kernel<<<N_WORDS, 64, 0, stream>>>(HS, outWT, outb, out);
}